// Round 1
// baseline (1063.498 us; speedup 1.0000x reference)
//
#include <hip/hip_runtime.h>
#include <hip/hip_bf16.h>
#include <math.h>

// Problem constants
#define B 16
#define A 1614            // total anchors/scores per batch
#define S1 1176           // 6*14*14
#define S2 294            // 6*7*7
#define S3 144            // 9*4*4
#define CROP 224
#define PADI 224

// d_out layout (floats):
//   [0, 25824)              rpn_score   (16,1614)
//   [25824, 25920)          top_n_index (16,6)  stored as float(j)
//   [25920, 26016)          top_n_prob  (16,6)
//   [26016, 4842912)        part_imgs   (16,6,3,224,224)

// ---------------- init d1 with bias (atomic K-split accumulates on top) ---------
__global__ void init_d1_kernel(const float* __restrict__ b1, float* __restrict__ d1) {
    int i = blockIdx.x * 256 + threadIdx.x;
    if (i < B * 128 * 196) d1[i] = b1[(i / 196) & 127];
}

// ---------------- conv1: 2048->128, 3x3, pad1, 14x14 ----------------------------
// grid (16 batch, 8 co-tiles of 16, 8 ci-splits of 256), block 256
// LDS-staged input subtiles (32 ci at a time, padded 16x16), scalar weight loads.
__global__ void conv1_kernel(const float* __restrict__ in,   // [16][2048][196]
                             const float* __restrict__ w,    // [128][2048][9]
                             float* __restrict__ d1)         // [16][128][196] (bias pre-init)
{
    __shared__ float lin[32][256];   // [ci][16*16] zero-padded
    const int b   = blockIdx.x;
    const int cog = blockIdx.y;      // co base = cog*16
    const int ci0 = blockIdx.z * 256;
    const int tid = threadIdx.x;

    // zero LDS once (borders stay zero across subtiles)
    for (int i = tid; i < 32 * 256; i += 256) ((float*)lin)[i] = 0.f;

    float acc[16];
#pragma unroll
    for (int j = 0; j < 16; j++) acc[j] = 0.f;

    const int pos = tid;             // output position, <196 active
    const int py = pos / 14, px = pos % 14;
    const bool active = pos < 196;

    for (int sub = 0; sub < 256; sub += 32) {
        __syncthreads();             // protect previous compute reads
        // stage 32 channels of 14x14 into padded LDS
        for (int i = tid; i < 32 * 196; i += 256) {
            int ci = i / 196, p = i - ci * 196;
            int yy = p / 14, xx = p - yy * 14;
            lin[ci][(yy + 1) * 16 + (xx + 1)] =
                in[(b * 2048 + ci0 + sub + ci) * 196 + p];
        }
        __syncthreads();
        if (active) {
            for (int ci = 0; ci < 32; ci++) {
                const float p0 = lin[ci][(py    ) * 16 + px    ];
                const float p1 = lin[ci][(py    ) * 16 + px + 1];
                const float p2 = lin[ci][(py    ) * 16 + px + 2];
                const float p3 = lin[ci][(py + 1) * 16 + px    ];
                const float p4 = lin[ci][(py + 1) * 16 + px + 1];
                const float p5 = lin[ci][(py + 1) * 16 + px + 2];
                const float p6 = lin[ci][(py + 2) * 16 + px    ];
                const float p7 = lin[ci][(py + 2) * 16 + px + 1];
                const float p8 = lin[ci][(py + 2) * 16 + px + 2];
                const int cig = ci0 + sub + ci;
#pragma unroll
                for (int co = 0; co < 16; co++) {
                    // uniform address -> scalar loads
                    const float* wc = w + ((cog * 16 + co) * 2048 + cig) * 9;
                    float a = acc[co];
                    a = fmaf(wc[0], p0, a);
                    a = fmaf(wc[1], p1, a);
                    a = fmaf(wc[2], p2, a);
                    a = fmaf(wc[3], p3, a);
                    a = fmaf(wc[4], p4, a);
                    a = fmaf(wc[5], p5, a);
                    a = fmaf(wc[6], p6, a);
                    a = fmaf(wc[7], p7, a);
                    a = fmaf(wc[8], p8, a);
                    acc[co] = a;
                }
            }
        }
    }
    if (active) {
#pragma unroll
        for (int co = 0; co < 16; co++)
            atomicAdd(&d1[(b * 128 + cog * 16 + co) * 196 + pos], acc[co]);
    }
}

// ---------------- conv2: 128->128, 3x3, stride2, pad1, 14x14 -> 7x7 -------------
// reads d1 (relu applied at read), writes relu(acc)
__global__ void conv2_kernel(const float* __restrict__ d1, const float* __restrict__ w,
                             const float* __restrict__ bias, float* __restrict__ d2)
{
    int idx = blockIdx.x * 256 + threadIdx.x;
    if (idx >= B * 128 * 49) return;
    int ox = idx % 7; int t = idx / 7;
    int oy = t % 7;  t /= 7;
    int co = t % 128; int b = t / 128;
    float acc = bias[co];
    const float* wp = w + co * 128 * 9;
    const float* ip = d1 + b * 128 * 196;
    for (int ci = 0; ci < 128; ci++) {
#pragma unroll
        for (int dy = 0; dy < 3; dy++) {
            int iy = 2 * oy - 1 + dy;
            if ((unsigned)iy >= 14u) continue;
#pragma unroll
            for (int dx = 0; dx < 3; dx++) {
                int ix = 2 * ox - 1 + dx;
                if ((unsigned)ix >= 14u) continue;
                acc = fmaf(fmaxf(ip[ci * 196 + iy * 14 + ix], 0.f),
                           wp[ci * 9 + dy * 3 + dx], acc);
            }
        }
    }
    d2[idx] = fmaxf(acc, 0.f);
}

// ---------------- conv3: 128->128, 3x3, stride2, pad1, 7x7 -> 4x4 ---------------
// d2 already relu'd; writes relu(acc)
__global__ void conv3_kernel(const float* __restrict__ d2, const float* __restrict__ w,
                             const float* __restrict__ bias, float* __restrict__ d3)
{
    int idx = blockIdx.x * 256 + threadIdx.x;
    if (idx >= B * 128 * 16) return;
    int ox = idx % 4; int t = idx / 4;
    int oy = t % 4;  t /= 4;
    int co = t % 128; int b = t / 128;
    float acc = bias[co];
    const float* wp = w + co * 128 * 9;
    const float* ip = d2 + b * 128 * 49;
    for (int ci = 0; ci < 128; ci++) {
#pragma unroll
        for (int dy = 0; dy < 3; dy++) {
            int iy = 2 * oy - 1 + dy;
            if ((unsigned)iy >= 7u) continue;
#pragma unroll
            for (int dx = 0; dx < 3; dx++) {
                int ix = 2 * ox - 1 + dx;
                if ((unsigned)ix >= 7u) continue;
                acc = fmaf(ip[ci * 49 + iy * 7 + ix],
                           wp[ci * 9 + dy * 3 + dx], acc);
            }
        }
    }
    d3[idx] = fmaxf(acc, 0.f);
}

// ---------------- tidy heads (1x1 convs) -> scores ------------------------------
__global__ void tidy_kernel(const float* __restrict__ d1, const float* __restrict__ d2,
                            const float* __restrict__ d3,
                            const float* __restrict__ wt1, const float* __restrict__ bt1,
                            const float* __restrict__ wt2, const float* __restrict__ bt2,
                            const float* __restrict__ wt3, const float* __restrict__ bt3,
                            float* __restrict__ scores)
{
    int idx = blockIdx.x * 256 + threadIdx.x;
    if (idx >= B * A) return;
    int b = idx / A, s = idx % A;
    float acc;
    if (s < S1) {
        int c = s / 196, pos = s - c * 196;
        const float* f = d1 + b * 128 * 196;
        const float* wv = wt1 + c * 128;
        acc = bt1[c];
        for (int ci = 0; ci < 128; ci++)
            acc = fmaf(fmaxf(f[ci * 196 + pos], 0.f), wv[ci], acc);   // relu at read
    } else if (s < S1 + S2) {
        int u = s - S1;
        int c = u / 49, pos = u - c * 49;
        const float* f = d2 + b * 128 * 49;
        const float* wv = wt2 + c * 128;
        acc = bt2[c];
        for (int ci = 0; ci < 128; ci++)
            acc = fmaf(f[ci * 49 + pos], wv[ci], acc);
    } else {
        int u = s - S1 - S2;
        int c = u / 16, pos = u - c * 16;
        const float* f = d3 + b * 128 * 16;
        const float* wv = wt3 + c * 128;
        acc = bt3[c];
        for (int ci = 0; ci < 128; ci++)
            acc = fmaf(f[ci * 16 + pos], wv[ci], acc);
    }
    scores[idx] = acc;
}

// ---------------- hard NMS (exact argmax semantics) -----------------------------
__global__ void nms_kernel(const float* __restrict__ scores, const int* __restrict__ anchors,
                           float* __restrict__ out_idx, float* __restrict__ out_prob,
                           int* __restrict__ boxes_out)
{
    __shared__ float sc[A];
    __shared__ float ay0[A], ax0[A], ay1[A], ax1[A], aarea[A];
    __shared__ float rv[256];
    __shared__ int   ri[256];
    __shared__ int   chosen;
    const int b = blockIdx.x, tid = threadIdx.x;

    for (int i = tid; i < A; i += 256) {
        sc[i] = scores[b * A + i];
        int y0 = anchors[i * 4 + 0], x0 = anchors[i * 4 + 1];
        int y1 = anchors[i * 4 + 2], x1 = anchors[i * 4 + 3];
        ay0[i] = (float)y0; ax0[i] = (float)x0;
        ay1[i] = (float)y1; ax1[i] = (float)x1;
        aarea[i] = (float)(y1 - y0) * (float)(x1 - x0);
    }
    __syncthreads();

    for (int it = 0; it < 6; it++) {
        // local argmax (first-index tie-break: strict > keeps earliest)
        float bv = -INFINITY; int bi = 0x7fffffff;
        for (int i = tid; i < A; i += 256) {
            if (sc[i] > bv) { bv = sc[i]; bi = i; }
        }
        rv[tid] = bv; ri[tid] = bi;
        __syncthreads();
        for (int s = 128; s > 0; s >>= 1) {
            if (tid < s) {
                if (rv[tid + s] > rv[tid] ||
                    (rv[tid + s] == rv[tid] && ri[tid + s] < ri[tid])) {
                    rv[tid] = rv[tid + s]; ri[tid] = ri[tid + s];
                }
            }
            __syncthreads();
        }
        if (tid == 0) {
            int j = ri[0];
            chosen = j;
            out_idx[b * 6 + it]  = (float)j;   // harness reads d_out as fp32
            out_prob[b * 6 + it] = rv[0];      // pre-suppression score of j
            boxes_out[(b * 6 + it) * 4 + 0] = anchors[j * 4 + 0];
            boxes_out[(b * 6 + it) * 4 + 1] = anchors[j * 4 + 1];
            boxes_out[(b * 6 + it) * 4 + 2] = anchors[j * 4 + 2];
            boxes_out[(b * 6 + it) * 4 + 3] = anchors[j * 4 + 3];
        }
        __syncthreads();
        const int j = chosen;
        const float jy0 = ay0[j], jx0 = ax0[j], jy1 = ay1[j], jx1 = ax1[j], ja = aarea[j];
        for (int i = tid; i < A; i += 256) {
            float yy0 = fmaxf(jy0, ay0[i]), xx0 = fmaxf(jx0, ax0[i]);
            float yy1 = fminf(jy1, ay1[i]), xx1 = fminf(jx1, ax1[i]);
            float inter = fmaxf(yy1 - yy0, 0.f) * fmaxf(xx1 - xx0, 0.f);
            float iou = inter / (ja + aarea[i] - inter);
            if (iou > 0.25f) sc[i] = -INFINITY;   // includes j itself (iou=1)
        }
        __syncthreads();
    }
}

// ---------------- crop + bilinear resize to 224x224 ----------------------------
__device__ __forceinline__ float sample_pad(const float* __restrict__ x,
                                            int bc, int y, int xx)
{
    y -= PADI; xx -= PADI;
    if ((unsigned)y < 448u && (unsigned)xx < 448u)
        return x[(bc * 448 + y) * 448 + xx];
    return 0.f;
}

__global__ void crop_kernel(const float* __restrict__ x, const int* __restrict__ boxes,
                            float* __restrict__ parts)
{
    int idx = blockIdx.x * 256 + threadIdx.x;   // < 16*6*3*224*224
    int ix = idx % 224; int t = idx / 224;
    int iy = t % 224;  t /= 224;
    int c  = t % 3;    t /= 3;
    int n  = t % 6;    int b = t / 6;

    const int* bx = boxes + (b * 6 + n) * 4;    // block-uniform
    const int y0 = bx[0], x0 = bx[1], y1 = bx[2], x1 = bx[3];

    float ty = (float)iy / 223.f;
    float tx = (float)ix / 223.f;
    float ys = (float)y0 + ty * (float)(y1 - y0 - 1);
    float xs = (float)x0 + tx * (float)(x1 - x0 - 1);
    int y0i = (int)floorf(ys);
    int x0i = (int)floorf(xs);
    float wy = ys - (float)y0i;
    float wx = xs - (float)x0i;
    int y1i = min(y0i + 1, 895);
    int x1i = min(x0i + 1, 895);

    const int bc = b * 3 + c;
    float v00 = sample_pad(x, bc, y0i, x0i);
    float v01 = sample_pad(x, bc, y0i, x1i);
    float v10 = sample_pad(x, bc, y1i, x0i);
    float v11 = sample_pad(x, bc, y1i, x1i);

    float v = v00 * (1.f - wy) * (1.f - wx) + v01 * (1.f - wy) * wx
            + v10 * wy * (1.f - wx)         + v11 * wy * wx;
    parts[idx] = v;
}

// ---------------- launcher ------------------------------------------------------
extern "C" void kernel_launch(void* const* d_in, const int* in_sizes, int n_in,
                              void* d_out, int out_size, void* d_ws, size_t ws_size,
                              hipStream_t stream)
{
    const float* x       = (const float*)d_in[0];
    const float* rpn     = (const float*)d_in[1];
    const int*   anchors = (const int*)  d_in[2];
    const float* w1  = (const float*)d_in[3];  const float* b1  = (const float*)d_in[4];
    const float* w2  = (const float*)d_in[5];  const float* b2  = (const float*)d_in[6];
    const float* w3  = (const float*)d_in[7];  const float* b3  = (const float*)d_in[8];
    const float* wt1 = (const float*)d_in[9];  const float* bt1 = (const float*)d_in[10];
    const float* wt2 = (const float*)d_in[11]; const float* bt2 = (const float*)d_in[12];
    const float* wt3 = (const float*)d_in[13]; const float* bt3 = (const float*)d_in[14];

    float* out = (float*)d_out;
    float* d1 = (float*)d_ws;                 // 16*128*196 = 401408
    float* d2 = d1 + 401408;                  // 16*128*49  = 100352
    float* d3 = d2 + 100352;                  // 16*128*16  = 32768
    int*   boxes = (int*)(d3 + 32768);        // 16*6*4 ints

    float* scores = out;                      // 16*1614
    float* oidx   = out + 25824;
    float* oprob  = out + 25920;
    float* parts  = out + 26016;

    init_d1_kernel<<<(B * 128 * 196 + 255) / 256, 256, 0, stream>>>(b1, d1);
    conv1_kernel<<<dim3(16, 8, 8), 256, 0, stream>>>(rpn, w1, d1);
    conv2_kernel<<<(B * 128 * 49 + 255) / 256, 256, 0, stream>>>(d1, w2, b2, d2);
    conv3_kernel<<<(B * 128 * 16 + 255) / 256, 256, 0, stream>>>(d2, w3, b3, d3);
    tidy_kernel<<<(B * A + 255) / 256, 256, 0, stream>>>(d1, d2, d3,
                                                         wt1, bt1, wt2, bt2, wt3, bt3,
                                                         scores);
    nms_kernel<<<16, 256, 0, stream>>>(scores, anchors, oidx, oprob, boxes);
    crop_kernel<<<(16 * 6 * 3 * 224 * 224) / 256, 256, 0, stream>>>(x, boxes, parts);
}

// Round 2
// 552.128 us; speedup vs baseline: 1.9262x; 1.9262x over previous
//
#include <hip/hip_runtime.h>
#include <hip/hip_bf16.h>
#include <math.h>

// Problem constants
#define B 16
#define A 1614            // total anchors/scores per batch
#define S1 1176           // 6*14*14
#define S2 294            // 6*7*7
#define S3 144            // 9*4*4
#define CROP 224
#define PADI 224

typedef __attribute__((ext_vector_type(8))) short short8;
typedef __attribute__((ext_vector_type(4))) float f32x4;

__device__ __forceinline__ unsigned short bf16u(float v) {
    union { __hip_bfloat16 h; unsigned short u; } cv;
    cv.h = __float2bfloat16(v);
    return cv.u;
}
__device__ __forceinline__ float bf16f(unsigned short u) {
    union { unsigned short u; __hip_bfloat16 h; } cv;
    cv.u = u;
    return __bfloat162float(cv.h);
}

// d_out layout (floats):
//   [0, 25824)              rpn_score   (16,1614)
//   [25824, 25920)          top_n_index (16,6)  stored as float(j)
//   [25920, 26016)          top_n_prob  (16,6)
//   [26016, 4842912)        part_imgs   (16,6,3,224,224)

// ---------------- init d1 with bias (atomic K-split accumulates on top) ---------
__global__ void init_d1_kernel(const float* __restrict__ b1, float* __restrict__ d1) {
    int i = blockIdx.x * 256 + threadIdx.x;
    if (i < B * 128 * 196) d1[i] = b1[(i / 196) & 127];
}

// ---------------- prepass: pack conv1 weights into MFMA A-fragments -------------
// chunk c = (ct*9 + tap)*64 + kidx ; ct in [0,8) (16 co each), kidx in [0,64) (32 ci)
// per chunk: 64 lanes x 8 bf16 = 1 KB, laid out exactly as one wave's A-frag load.
// A-layout (verified m89/m120): A[m = lane&15][k = (lane>>4)*8 + j]
__global__ void pack_w_kernel(const float* __restrict__ w,   // [128][2048][9]
                              unsigned short* __restrict__ wh,
                              unsigned short* __restrict__ wl)
{
    int chunk = blockIdx.x * 4 + (threadIdx.x >> 6);   // 4608 chunks
    int lane = threadIdx.x & 63;
    int kidx = chunk & 63;
    int q = chunk >> 6;
    int t = q % 9, ct = q / 9;
    int co = ct * 16 + (lane & 15);
    int ci0 = kidx * 32 + (lane >> 4) * 8;
    short8 h8, l8;
#pragma unroll
    for (int j = 0; j < 8; j++) {
        float v = w[(co * 2048 + ci0 + j) * 9 + t];
        unsigned short h = bf16u(v);
        h8[j] = (short)h;
        l8[j] = (short)bf16u(v - bf16f(h));
    }
    *(short8*)(wh + (size_t)chunk * 512 + lane * 8) = h8;
    *(short8*)(wl + (size_t)chunk * 512 + lane * 8) = l8;
}

// ---------------- conv1 via MFMA: 2048->128, 3x3, pad1, 14x14 -------------------
// grid (16 b, 4 co-groups of 32, 8 K-splits of 256 ci), block 256 (4 waves).
// Per wave: 2 M-tiles (16 co each) x 13 N-tiles (196 pos padded to 208).
// bf16 hi/lo 3-product accumulation in fp32 for ~fp32 accuracy.
// Input staged per 64-ci group into LDS padded 16x16 planes: Xh[2][256][32] + Xl.
__global__ void __launch_bounds__(256, 2)
conv1_mfma_kernel(const float* __restrict__ in,                  // [16][2048][196]
                  const unsigned short* __restrict__ wh,
                  const unsigned short* __restrict__ wl,
                  float* __restrict__ d1)                        // [16][128][196]
{
    __shared__ short lds[32768];   // 64 KB: Xh at [0,16384), Xl at [16384,32768)
    const int b   = blockIdx.x;
    const int ctg = blockIdx.y;    // 0..3  -> co base ctg*32
    const int ks  = blockIdx.z;    // 0..7  -> ci base ks*256
    const int tid = threadIdx.x;
    const int wave = tid >> 6, lane = tid & 63;
    const int quad = lane >> 4;

    // per-lane B-fragment base offsets (in shorts) for 13 N-tiles
    int bbase[13];
#pragma unroll
    for (int nt = 0; nt < 13; nt++) {
        int pos = nt * 16 + (lane & 15);
        int py = pos / 14, px = pos % 14;
        int plane = (pos < 196) ? ((py + 1) * 16 + (px + 1)) : 17;  // invalid lanes read valid garbage, masked at epilogue
        bbase[nt] = plane * 32 + quad * 8;
    }

    f32x4 acc[2][13];
#pragma unroll
    for (int m = 0; m < 2; m++)
#pragma unroll
        for (int nt = 0; nt < 13; nt++)
            acc[m][nt] = (f32x4){0.f, 0.f, 0.f, 0.f};

    // zero LDS once (zero-padded plane borders persist across groups)
    for (int i = tid; i < 16384; i += 256) ((int*)lds)[i] = 0;
    __syncthreads();

    const int ci_base = ks * 256;
    for (int g = 0; g < 4; g++) {           // 4 groups of 64 ci
        if (g) __syncthreads();
        // stage 64 ci: thread handles (8-ci block, position) -> one b128 write per region
        for (int i = tid; i < 8 * 196; i += 256) {
            int blk = i / 196, p = i - blk * 196;
            int py = p / 14, px = p - py * 14;
            int plane = (py + 1) * 16 + (px + 1);
            const float* src = in + (size_t)(b * 2048 + ci_base + g * 64 + blk * 8) * 196 + p;
            short8 h8, l8;
#pragma unroll
            for (int j = 0; j < 8; j++) {
                float v = src[j * 196];
                unsigned short h = bf16u(v);
                h8[j] = (short)h;
                l8[j] = (short)bf16u(v - bf16f(h));
            }
            int kc = blk >> 2;
            int off = (kc * 256 + plane) * 32 + (blk & 3) * 8;
            *(short8*)&lds[off] = h8;
            *(short8*)&lds[16384 + off] = l8;
        }
        __syncthreads();
        // 18 units (9 taps x 2 k-chunks) dealt to 4 waves, class rotated per group
        int cls = (wave + g) & 3;
        for (int k = 0; k < 5; k++) {
            int u = k * 4 + cls;
            if (u >= 18) break;
            int tap = u >> 1, kc = u & 1;
            int dy = tap / 3, dx = tap - dy * 3;
            int tapoff = ((dy - 1) * 16 + (dx - 1)) * 32;          // shorts
            int kidx = ks * 8 + g * 2 + kc;                        // global 32-ci chunk
            size_t c0 = (size_t)(((ctg * 2 + 0) * 9 + tap) * 64 + kidx) * 512 + lane * 8;
            size_t c1 = (size_t)(((ctg * 2 + 1) * 9 + tap) * 64 + kidx) * 512 + lane * 8;
            const short8 ah0 = *(const short8*)(wh + c0);
            const short8 al0 = *(const short8*)(wl + c0);
            const short8 ah1 = *(const short8*)(wh + c1);
            const short8 al1 = *(const short8*)(wl + c1);
#pragma unroll
            for (int nt = 0; nt < 13; nt++) {
                int idx = kc * 8192 + bbase[nt] + tapoff;
                short8 bh = *(const short8*)&lds[idx];
                short8 bl = *(const short8*)&lds[16384 + idx];
                acc[0][nt] = __builtin_amdgcn_mfma_f32_16x16x32_bf16(ah0, bh, acc[0][nt], 0, 0, 0);
                acc[1][nt] = __builtin_amdgcn_mfma_f32_16x16x32_bf16(ah1, bh, acc[1][nt], 0, 0, 0);
                acc[0][nt] = __builtin_amdgcn_mfma_f32_16x16x32_bf16(ah0, bl, acc[0][nt], 0, 0, 0);
                acc[1][nt] = __builtin_amdgcn_mfma_f32_16x16x32_bf16(ah1, bl, acc[1][nt], 0, 0, 0);
                acc[0][nt] = __builtin_amdgcn_mfma_f32_16x16x32_bf16(al0, bh, acc[0][nt], 0, 0, 0);
                acc[1][nt] = __builtin_amdgcn_mfma_f32_16x16x32_bf16(al1, bh, acc[1][nt], 0, 0, 0);
            }
        }
    }

    // reduce the 4 waves' K-partials in LDS, then one atomicAdd set per block
    __syncthreads();
    float* red = (float*)lds;   // 2*13*4*64 = 6656 floats
    for (int w = 0; w < 4; w++) {
        if (wave == w) {
#pragma unroll
            for (int m = 0; m < 2; m++)
#pragma unroll
                for (int nt = 0; nt < 13; nt++)
#pragma unroll
                    for (int r = 0; r < 4; r++) {
                        int slot = ((m * 13 + nt) * 4 + r) * 64 + lane;
                        float v = acc[m][nt][r];
                        if (w == 0) red[slot] = v; else red[slot] += v;
                    }
        }
        __syncthreads();
    }
    // D-layout (verified m89): col = lane&15 (pos), row = (lane>>4)*4 + reg (co)
    for (int s = tid; s < 2 * 13 * 4 * 64; s += 256) {
        int lane_s = s & 63;
        int r = (s >> 6) & 3;
        int nt = (s >> 8) % 13;
        int m = (s >> 8) / 13;
        int pos = nt * 16 + (lane_s & 15);
        if (pos < 196) {
            int co = ctg * 32 + m * 16 + (lane_s >> 4) * 4 + r;
            atomicAdd(&d1[(size_t)(b * 128 + co) * 196 + pos], red[s]);
        }
    }
}

// ---------------- conv2: 128->128, 3x3, stride2, pad1, 14x14 -> 7x7 -------------
__global__ void conv2_kernel(const float* __restrict__ d1, const float* __restrict__ w,
                             const float* __restrict__ bias, float* __restrict__ d2)
{
    int idx = blockIdx.x * 256 + threadIdx.x;
    if (idx >= B * 128 * 49) return;
    int ox = idx % 7; int t = idx / 7;
    int oy = t % 7;  t /= 7;
    int co = t % 128; int b = t / 128;
    float acc = bias[co];
    const float* wp = w + co * 128 * 9;
    const float* ip = d1 + b * 128 * 196;
    for (int ci = 0; ci < 128; ci++) {
#pragma unroll
        for (int dy = 0; dy < 3; dy++) {
            int iy = 2 * oy - 1 + dy;
            if ((unsigned)iy >= 14u) continue;
#pragma unroll
            for (int dx = 0; dx < 3; dx++) {
                int ix = 2 * ox - 1 + dx;
                if ((unsigned)ix >= 14u) continue;
                acc = fmaf(fmaxf(ip[ci * 196 + iy * 14 + ix], 0.f),
                           wp[ci * 9 + dy * 3 + dx], acc);
            }
        }
    }
    d2[idx] = fmaxf(acc, 0.f);
}

// ---------------- conv3: 128->128, 3x3, stride2, pad1, 7x7 -> 4x4 ---------------
__global__ void conv3_kernel(const float* __restrict__ d2, const float* __restrict__ w,
                             const float* __restrict__ bias, float* __restrict__ d3)
{
    int idx = blockIdx.x * 256 + threadIdx.x;
    if (idx >= B * 128 * 16) return;
    int ox = idx % 4; int t = idx / 4;
    int oy = t % 4;  t /= 4;
    int co = t % 128; int b = t / 128;
    float acc = bias[co];
    const float* wp = w + co * 128 * 9;
    const float* ip = d2 + b * 128 * 49;
    for (int ci = 0; ci < 128; ci++) {
#pragma unroll
        for (int dy = 0; dy < 3; dy++) {
            int iy = 2 * oy - 1 + dy;
            if ((unsigned)iy >= 7u) continue;
#pragma unroll
            for (int dx = 0; dx < 3; dx++) {
                int ix = 2 * ox - 1 + dx;
                if ((unsigned)ix >= 7u) continue;
                acc = fmaf(ip[ci * 49 + iy * 7 + ix],
                           wp[ci * 9 + dy * 3 + dx], acc);
            }
        }
    }
    d3[idx] = fmaxf(acc, 0.f);
}

// ---------------- tidy heads (1x1 convs) -> scores ------------------------------
__global__ void tidy_kernel(const float* __restrict__ d1, const float* __restrict__ d2,
                            const float* __restrict__ d3,
                            const float* __restrict__ wt1, const float* __restrict__ bt1,
                            const float* __restrict__ wt2, const float* __restrict__ bt2,
                            const float* __restrict__ wt3, const float* __restrict__ bt3,
                            float* __restrict__ scores)
{
    int idx = blockIdx.x * 256 + threadIdx.x;
    if (idx >= B * A) return;
    int b = idx / A, s = idx % A;
    float acc;
    if (s < S1) {
        int c = s / 196, pos = s - c * 196;
        const float* f = d1 + b * 128 * 196;
        const float* wv = wt1 + c * 128;
        acc = bt1[c];
        for (int ci = 0; ci < 128; ci++)
            acc = fmaf(fmaxf(f[ci * 196 + pos], 0.f), wv[ci], acc);
    } else if (s < S1 + S2) {
        int u = s - S1;
        int c = u / 49, pos = u - c * 49;
        const float* f = d2 + b * 128 * 49;
        const float* wv = wt2 + c * 128;
        acc = bt2[c];
        for (int ci = 0; ci < 128; ci++)
            acc = fmaf(f[ci * 49 + pos], wv[ci], acc);
    } else {
        int u = s - S1 - S2;
        int c = u / 16, pos = u - c * 16;
        const float* f = d3 + b * 128 * 16;
        const float* wv = wt3 + c * 128;
        acc = bt3[c];
        for (int ci = 0; ci < 128; ci++)
            acc = fmaf(f[ci * 16 + pos], wv[ci], acc);
    }
    scores[idx] = acc;
}

// ---------------- hard NMS (exact argmax semantics) -----------------------------
__global__ void nms_kernel(const float* __restrict__ scores, const int* __restrict__ anchors,
                           float* __restrict__ out_idx, float* __restrict__ out_prob,
                           int* __restrict__ boxes_out)
{
    __shared__ float sc[A];
    __shared__ float ay0[A], ax0[A], ay1[A], ax1[A], aarea[A];
    __shared__ float rv[256];
    __shared__ int   ri[256];
    __shared__ int   chosen;
    const int b = blockIdx.x, tid = threadIdx.x;

    for (int i = tid; i < A; i += 256) {
        sc[i] = scores[b * A + i];
        int y0 = anchors[i * 4 + 0], x0 = anchors[i * 4 + 1];
        int y1 = anchors[i * 4 + 2], x1 = anchors[i * 4 + 3];
        ay0[i] = (float)y0; ax0[i] = (float)x0;
        ay1[i] = (float)y1; ax1[i] = (float)x1;
        aarea[i] = (float)(y1 - y0) * (float)(x1 - x0);
    }
    __syncthreads();

    for (int it = 0; it < 6; it++) {
        float bv = -INFINITY; int bi = 0x7fffffff;
        for (int i = tid; i < A; i += 256) {
            if (sc[i] > bv) { bv = sc[i]; bi = i; }
        }
        rv[tid] = bv; ri[tid] = bi;
        __syncthreads();
        for (int s = 128; s > 0; s >>= 1) {
            if (tid < s) {
                if (rv[tid + s] > rv[tid] ||
                    (rv[tid + s] == rv[tid] && ri[tid + s] < ri[tid])) {
                    rv[tid] = rv[tid + s]; ri[tid] = ri[tid + s];
                }
            }
            __syncthreads();
        }
        if (tid == 0) {
            int j = ri[0];
            chosen = j;
            out_idx[b * 6 + it]  = (float)j;
            out_prob[b * 6 + it] = rv[0];
            boxes_out[(b * 6 + it) * 4 + 0] = anchors[j * 4 + 0];
            boxes_out[(b * 6 + it) * 4 + 1] = anchors[j * 4 + 1];
            boxes_out[(b * 6 + it) * 4 + 2] = anchors[j * 4 + 2];
            boxes_out[(b * 6 + it) * 4 + 3] = anchors[j * 4 + 3];
        }
        __syncthreads();
        const int j = chosen;
        const float jy0 = ay0[j], jx0 = ax0[j], jy1 = ay1[j], jx1 = ax1[j], ja = aarea[j];
        for (int i = tid; i < A; i += 256) {
            float yy0 = fmaxf(jy0, ay0[i]), xx0 = fmaxf(jx0, ax0[i]);
            float yy1 = fminf(jy1, ay1[i]), xx1 = fminf(jx1, ax1[i]);
            float inter = fmaxf(yy1 - yy0, 0.f) * fmaxf(xx1 - xx0, 0.f);
            float iou = inter / (ja + aarea[i] - inter);
            if (iou > 0.25f) sc[i] = -INFINITY;
        }
        __syncthreads();
    }
}

// ---------------- crop + bilinear resize to 224x224 ----------------------------
__device__ __forceinline__ float sample_pad(const float* __restrict__ x,
                                            int bc, int y, int xx)
{
    y -= PADI; xx -= PADI;
    if ((unsigned)y < 448u && (unsigned)xx < 448u)
        return x[(bc * 448 + y) * 448 + xx];
    return 0.f;
}

__global__ void crop_kernel(const float* __restrict__ x, const int* __restrict__ boxes,
                            float* __restrict__ parts)
{
    int idx = blockIdx.x * 256 + threadIdx.x;
    int ix = idx % 224; int t = idx / 224;
    int iy = t % 224;  t /= 224;
    int c  = t % 3;    t /= 3;
    int n  = t % 6;    int b = t / 6;

    const int* bx = boxes + (b * 6 + n) * 4;
    const int y0 = bx[0], x0 = bx[1], y1 = bx[2], x1 = bx[3];

    float ty = (float)iy / 223.f;
    float tx = (float)ix / 223.f;
    float ys = (float)y0 + ty * (float)(y1 - y0 - 1);
    float xs = (float)x0 + tx * (float)(x1 - x0 - 1);
    int y0i = (int)floorf(ys);
    int x0i = (int)floorf(xs);
    float wy = ys - (float)y0i;
    float wx = xs - (float)x0i;
    int y1i = min(y0i + 1, 895);
    int x1i = min(x0i + 1, 895);

    const int bc = b * 3 + c;
    float v00 = sample_pad(x, bc, y0i, x0i);
    float v01 = sample_pad(x, bc, y0i, x1i);
    float v10 = sample_pad(x, bc, y1i, x0i);
    float v11 = sample_pad(x, bc, y1i, x1i);

    float v = v00 * (1.f - wy) * (1.f - wx) + v01 * (1.f - wy) * wx
            + v10 * wy * (1.f - wx)         + v11 * wy * wx;
    parts[idx] = v;
}

// ---------------- launcher ------------------------------------------------------
extern "C" void kernel_launch(void* const* d_in, const int* in_sizes, int n_in,
                              void* d_out, int out_size, void* d_ws, size_t ws_size,
                              hipStream_t stream)
{
    const float* x       = (const float*)d_in[0];
    const float* rpn     = (const float*)d_in[1];
    const int*   anchors = (const int*)  d_in[2];
    const float* w1  = (const float*)d_in[3];  const float* b1  = (const float*)d_in[4];
    const float* w2  = (const float*)d_in[5];  const float* b2  = (const float*)d_in[6];
    const float* w3  = (const float*)d_in[7];  const float* b3  = (const float*)d_in[8];
    const float* wt1 = (const float*)d_in[9];  const float* bt1 = (const float*)d_in[10];
    const float* wt2 = (const float*)d_in[11]; const float* bt2 = (const float*)d_in[12];
    const float* wt3 = (const float*)d_in[13]; const float* bt3 = (const float*)d_in[14];

    float* out = (float*)d_out;
    float* d1 = (float*)d_ws;                 // 401408 floats
    float* d2 = d1 + 401408;                  // 100352
    float* d3 = d2 + 100352;                  // 32768
    int*   boxes = (int*)(d3 + 32768);        // 384 ints
    unsigned short* wh = (unsigned short*)((float*)d_ws + 534624);   // 2359296 ushorts (4.72 MB), 16B-aligned
    unsigned short* wl = wh + 2359296;                               // 2359296 ushorts

    float* scores = out;                      // 16*1614
    float* oidx   = out + 25824;
    float* oprob  = out + 25920;
    float* parts  = out + 26016;

    pack_w_kernel<<<1152, 256, 0, stream>>>(w1, wh, wl);
    init_d1_kernel<<<(B * 128 * 196 + 255) / 256, 256, 0, stream>>>(b1, d1);
    conv1_mfma_kernel<<<dim3(16, 4, 8), 256, 0, stream>>>(rpn, wh, wl, d1);
    conv2_kernel<<<(B * 128 * 49 + 255) / 256, 256, 0, stream>>>(d1, w2, b2, d2);
    conv3_kernel<<<(B * 128 * 16 + 255) / 256, 256, 0, stream>>>(d2, w3, b3, d3);
    tidy_kernel<<<(B * A + 255) / 256, 256, 0, stream>>>(d1, d2, d3,
                                                         wt1, bt1, wt2, bt2, wt3, bt3,
                                                         scores);
    nms_kernel<<<16, 256, 0, stream>>>(scores, anchors, oidx, oprob, boxes);
    crop_kernel<<<(16 * 6 * 3 * 224 * 224) / 256, 256, 0, stream>>>(x, boxes, parts);
}

// Round 3
// 341.268 us; speedup vs baseline: 3.1163x; 1.6179x over previous
//
#include <hip/hip_runtime.h>
#include <hip/hip_bf16.h>
#include <math.h>

// Problem constants
#define B 16
#define A 1614            // total anchors/scores per batch
#define S1 1176           // 6*14*14
#define S2 294            // 6*7*7
#define S3 144            // 9*4*4
#define CROP 224
#define PADI 224

typedef __attribute__((ext_vector_type(8))) short short8;
typedef __attribute__((ext_vector_type(4))) float f32x4;

__device__ __forceinline__ unsigned short bf16u(float v) {
    union { __hip_bfloat16 h; unsigned short u; } cv;
    cv.h = __float2bfloat16(v);
    return cv.u;
}
__device__ __forceinline__ float bf16f(unsigned short u) {
    union { unsigned short u; __hip_bfloat16 h; } cv;
    cv.u = u;
    return __bfloat162float(cv.h);
}

// d_out layout (floats):
//   [0, 25824)              rpn_score   (16,1614)
//   [25824, 25920)          top_n_index (16,6)  stored as float(j)
//   [25920, 26016)          top_n_prob  (16,6)
//   [26016, 4842912)        part_imgs   (16,6,3,224,224)

// ---------------- init d1 with bias (atomic K-split accumulates on top) ---------
__global__ void init_d1_kernel(const float* __restrict__ b1, float* __restrict__ d1) {
    int i = blockIdx.x * 256 + threadIdx.x;
    if (i < B * 128 * 196) d1[i] = b1[(i / 196) & 127];
}

// ---------------- prepass: pack conv1 weights into MFMA A-fragments -------------
__global__ void pack_w_kernel(const float* __restrict__ w,   // [128][2048][9]
                              unsigned short* __restrict__ wh,
                              unsigned short* __restrict__ wl)
{
    int chunk = blockIdx.x * 4 + (threadIdx.x >> 6);   // 4608 chunks
    int lane = threadIdx.x & 63;
    int kidx = chunk & 63;
    int q = chunk >> 6;
    int t = q % 9, ct = q / 9;
    int co = ct * 16 + (lane & 15);
    int ci0 = kidx * 32 + (lane >> 4) * 8;
    short8 h8, l8;
#pragma unroll
    for (int j = 0; j < 8; j++) {
        float v = w[(co * 2048 + ci0 + j) * 9 + t];
        unsigned short h = bf16u(v);
        h8[j] = (short)h;
        l8[j] = (short)bf16u(v - bf16f(h));
    }
    *(short8*)(wh + (size_t)chunk * 512 + lane * 8) = h8;
    *(short8*)(wl + (size_t)chunk * 512 + lane * 8) = l8;
}

// ---------------- conv1 via MFMA: 2048->128, 3x3, pad1, 14x14 -------------------
__global__ void __launch_bounds__(256, 2)
conv1_mfma_kernel(const float* __restrict__ in,                  // [16][2048][196]
                  const unsigned short* __restrict__ wh,
                  const unsigned short* __restrict__ wl,
                  float* __restrict__ d1)                        // [16][128][196]
{
    __shared__ short lds[32768];   // 64 KB: Xh at [0,16384), Xl at [16384,32768)
    const int b   = blockIdx.x;
    const int ctg = blockIdx.y;    // 0..3  -> co base ctg*32
    const int ks  = blockIdx.z;    // 0..7  -> ci base ks*256
    const int tid = threadIdx.x;
    const int wave = tid >> 6, lane = tid & 63;
    const int quad = lane >> 4;

    int bbase[13];
#pragma unroll
    for (int nt = 0; nt < 13; nt++) {
        int pos = nt * 16 + (lane & 15);
        int py = pos / 14, px = pos % 14;
        int plane = (pos < 196) ? ((py + 1) * 16 + (px + 1)) : 17;
        bbase[nt] = plane * 32 + quad * 8;
    }

    f32x4 acc[2][13];
#pragma unroll
    for (int m = 0; m < 2; m++)
#pragma unroll
        for (int nt = 0; nt < 13; nt++)
            acc[m][nt] = (f32x4){0.f, 0.f, 0.f, 0.f};

    for (int i = tid; i < 16384; i += 256) ((int*)lds)[i] = 0;
    __syncthreads();

    const int ci_base = ks * 256;
    for (int g = 0; g < 4; g++) {           // 4 groups of 64 ci
        if (g) __syncthreads();
        for (int i = tid; i < 8 * 196; i += 256) {
            int blk = i / 196, p = i - blk * 196;
            int py = p / 14, px = p - py * 14;
            int plane = (py + 1) * 16 + (px + 1);
            const float* src = in + (size_t)(b * 2048 + ci_base + g * 64 + blk * 8) * 196 + p;
            short8 h8, l8;
#pragma unroll
            for (int j = 0; j < 8; j++) {
                float v = src[j * 196];
                unsigned short h = bf16u(v);
                h8[j] = (short)h;
                l8[j] = (short)bf16u(v - bf16f(h));
            }
            int kc = blk >> 2;
            int off = (kc * 256 + plane) * 32 + (blk & 3) * 8;
            *(short8*)&lds[off] = h8;
            *(short8*)&lds[16384 + off] = l8;
        }
        __syncthreads();
        int cls = (wave + g) & 3;
        for (int k = 0; k < 5; k++) {
            int u = k * 4 + cls;
            if (u >= 18) break;
            int tap = u >> 1, kc = u & 1;
            int dy = tap / 3, dx = tap - dy * 3;
            int tapoff = ((dy - 1) * 16 + (dx - 1)) * 32;          // shorts
            int kidx = ks * 8 + g * 2 + kc;                        // global 32-ci chunk
            size_t c0 = (size_t)(((ctg * 2 + 0) * 9 + tap) * 64 + kidx) * 512 + lane * 8;
            size_t c1 = (size_t)(((ctg * 2 + 1) * 9 + tap) * 64 + kidx) * 512 + lane * 8;
            const short8 ah0 = *(const short8*)(wh + c0);
            const short8 al0 = *(const short8*)(wl + c0);
            const short8 ah1 = *(const short8*)(wh + c1);
            const short8 al1 = *(const short8*)(wl + c1);
#pragma unroll
            for (int nt = 0; nt < 13; nt++) {
                int idx = kc * 8192 + bbase[nt] + tapoff;
                short8 bh = *(const short8*)&lds[idx];
                short8 bl = *(const short8*)&lds[16384 + idx];
                acc[0][nt] = __builtin_amdgcn_mfma_f32_16x16x32_bf16(ah0, bh, acc[0][nt], 0, 0, 0);
                acc[1][nt] = __builtin_amdgcn_mfma_f32_16x16x32_bf16(ah1, bh, acc[1][nt], 0, 0, 0);
                acc[0][nt] = __builtin_amdgcn_mfma_f32_16x16x32_bf16(ah0, bl, acc[0][nt], 0, 0, 0);
                acc[1][nt] = __builtin_amdgcn_mfma_f32_16x16x32_bf16(ah1, bl, acc[1][nt], 0, 0, 0);
                acc[0][nt] = __builtin_amdgcn_mfma_f32_16x16x32_bf16(al0, bh, acc[0][nt], 0, 0, 0);
                acc[1][nt] = __builtin_amdgcn_mfma_f32_16x16x32_bf16(al1, bh, acc[1][nt], 0, 0, 0);
            }
        }
    }

    __syncthreads();
    float* red = (float*)lds;   // 2*13*4*64 = 6656 floats
    for (int w = 0; w < 4; w++) {
        if (wave == w) {
#pragma unroll
            for (int m = 0; m < 2; m++)
#pragma unroll
                for (int nt = 0; nt < 13; nt++)
#pragma unroll
                    for (int r = 0; r < 4; r++) {
                        int slot = ((m * 13 + nt) * 4 + r) * 64 + lane;
                        float v = acc[m][nt][r];
                        if (w == 0) red[slot] = v; else red[slot] += v;
                    }
        }
        __syncthreads();
    }
    for (int s = tid; s < 2 * 13 * 4 * 64; s += 256) {
        int lane_s = s & 63;
        int r = (s >> 6) & 3;
        int nt = (s >> 8) % 13;
        int m = (s >> 8) / 13;
        int pos = nt * 16 + (lane_s & 15);
        if (pos < 196) {
            int co = ctg * 32 + m * 16 + (lane_s >> 4) * 4 + r;
            atomicAdd(&d1[(size_t)(b * 128 + co) * 196 + pos], red[s]);
        }
    }
}

// ---------------- transpose d1 -> relu(d1) as [b][pos][co] ----------------------
__global__ void trans_d1_kernel(const float* __restrict__ d1, float* __restrict__ d1t)
{
    int i = blockIdx.x * 256 + threadIdx.x;   // 16*196*128
    int co = i & 127; int t = i >> 7;
    int pos = t % 196; int b = t / 196;
    d1t[i] = fmaxf(d1[(b * 128 + co) * 196 + pos], 0.f);
}

// ---------------- conv2: 128->128, 3x3, stride2, pad1, 14x14 -> 7x7 -------------
// grid (16 b, 8 cog of 16 co), block 256 (4 waves). Wave-uniform co -> scalar
// weight loads; lanes = output positions; input LDS-staged in 2 ci-halves.
__global__ void __launch_bounds__(256)
conv2_kernel(const float* __restrict__ d1, const float* __restrict__ w,
             const float* __restrict__ bias, float* __restrict__ d2,
             float* __restrict__ d2t)
{
    __shared__ float s1[64 * 196];    // 49 KB
    const int b = blockIdx.x, cog = blockIdx.y;
    const int tid = threadIdx.x;
    const int wave = __builtin_amdgcn_readfirstlane(tid >> 6);
    const int lane = tid & 63;
    const int pos = lane;
    const bool act = pos < 49;
    const int oy = pos / 7, ox = pos % 7;

    int off[9]; float msk[9];
#pragma unroll
    for (int dy = 0; dy < 3; dy++)
#pragma unroll
        for (int dx = 0; dx < 3; dx++) {
            int iy = 2 * oy - 1 + dy, ix = 2 * ox - 1 + dx;
            bool v = act && (unsigned)iy < 14u && (unsigned)ix < 14u;
            off[dy * 3 + dx] = v ? iy * 14 + ix : 0;
            msk[dy * 3 + dx] = v ? 1.f : 0.f;
        }

    const int co0 = cog * 16 + wave * 4;
    float acc0 = bias[co0], acc1 = bias[co0 + 1], acc2 = bias[co0 + 2], acc3 = bias[co0 + 3];

    for (int h = 0; h < 2; h++) {
        if (h) __syncthreads();
        for (int i = tid; i < 64 * 196; i += 256)
            s1[i] = fmaxf(d1[b * 25088 + h * 12544 + i], 0.f);
        __syncthreads();
        for (int ci = 0; ci < 64; ci++) {
            const float* base = s1 + ci * 196;
            float t[9];
#pragma unroll
            for (int k = 0; k < 9; k++) t[k] = msk[k] * base[off[k]];
            const int cig = h * 64 + ci;
            const float* wp0 = w + (size_t)((co0    ) * 128 + cig) * 9;
            const float* wp1 = w + (size_t)((co0 + 1) * 128 + cig) * 9;
            const float* wp2 = w + (size_t)((co0 + 2) * 128 + cig) * 9;
            const float* wp3 = w + (size_t)((co0 + 3) * 128 + cig) * 9;
#pragma unroll
            for (int k = 0; k < 9; k++) {
                acc0 = fmaf(t[k], wp0[k], acc0);
                acc1 = fmaf(t[k], wp1[k], acc1);
                acc2 = fmaf(t[k], wp2[k], acc2);
                acc3 = fmaf(t[k], wp3[k], acc3);
            }
        }
    }
    if (act) {
        float r0 = fmaxf(acc0, 0.f), r1 = fmaxf(acc1, 0.f);
        float r2 = fmaxf(acc2, 0.f), r3 = fmaxf(acc3, 0.f);
        d2[(b * 128 + co0    ) * 49 + pos] = r0;
        d2[(b * 128 + co0 + 1) * 49 + pos] = r1;
        d2[(b * 128 + co0 + 2) * 49 + pos] = r2;
        d2[(b * 128 + co0 + 3) * 49 + pos] = r3;
        float* dt = d2t + (b * 49 + pos) * 128 + co0;
        dt[0] = r0; dt[1] = r1; dt[2] = r2; dt[3] = r3;
    }
}

// ---------------- conv3: 128->128, 3x3, stride2, pad1, 7x7 -> 4x4 ---------------
// grid (16 b, 8 cog of 16 co), block 256, thread = (co_l, pos), input LDS-staged.
__global__ void __launch_bounds__(256)
conv3_kernel(const float* __restrict__ d2, const float* __restrict__ w,
             const float* __restrict__ bias, float* __restrict__ d3t)
{
    __shared__ float s2[128 * 49];    // 25 KB (already relu'd)
    const int b = blockIdx.x, cog = blockIdx.y;
    const int tid = threadIdx.x;
    for (int i = tid; i < 128 * 49; i += 256) s2[i] = d2[b * 6272 + i];
    __syncthreads();

    const int co = cog * 16 + (tid >> 4);
    const int pos = tid & 15, oy = pos >> 2, ox = pos & 3;
    int off[9]; float msk[9];
#pragma unroll
    for (int dy = 0; dy < 3; dy++)
#pragma unroll
        for (int dx = 0; dx < 3; dx++) {
            int iy = 2 * oy - 1 + dy, ix = 2 * ox - 1 + dx;
            bool v = (unsigned)iy < 7u && (unsigned)ix < 7u;
            off[dy * 3 + dx] = v ? iy * 7 + ix : 0;
            msk[dy * 3 + dx] = v ? 1.f : 0.f;
        }
    float acc = bias[co];
    const float* wp = w + (size_t)co * 1152;
    for (int ci = 0; ci < 128; ci++) {
        const float* base = s2 + ci * 49;
        const float* wc = wp + ci * 9;
#pragma unroll
        for (int k = 0; k < 9; k++)
            acc = fmaf(msk[k] * base[off[k]], wc[k], acc);
    }
    d3t[(b * 16 + pos) * 128 + co] = fmaxf(acc, 0.f);
}

// ---------------- tidy heads: one wave per score, coalesced transposed reads ----
__global__ void __launch_bounds__(256)
tidy_kernel(const float* __restrict__ d1t, const float* __restrict__ d2t,
            const float* __restrict__ d3t,
            const float* __restrict__ wt1, const float* __restrict__ bt1,
            const float* __restrict__ wt2, const float* __restrict__ bt2,
            const float* __restrict__ wt3, const float* __restrict__ bt3,
            float* __restrict__ scores)
{
    int gw = blockIdx.x * 4 + (threadIdx.x >> 6);   // wave id = b*A + s, 25824 total
    int lane = threadIdx.x & 63;
    int b = gw / A, s = gw - b * A;
    const float *f, *wv; float bias;
    if (s < S1) {
        int c = s / 196, pos = s - c * 196;
        f = d1t + (b * 196 + pos) * 128; wv = wt1 + c * 128; bias = bt1[c];
    } else if (s < S1 + S2) {
        int u = s - S1; int c = u / 49, pos = u - c * 49;
        f = d2t + (b * 49 + pos) * 128; wv = wt2 + c * 128; bias = bt2[c];
    } else {
        int u = s - S1 - S2; int c = u / 16, pos = u - c * 16;
        f = d3t + (b * 16 + pos) * 128; wv = wt3 + c * 128; bias = bt3[c];
    }
    float a = f[lane] * wv[lane] + f[lane + 64] * wv[lane + 64];
#pragma unroll
    for (int m = 32; m; m >>= 1) a += __shfl_xor(a, m, 64);
    if (lane == 0) scores[gw] = a + bias;
}

// ---------------- hard NMS (exact argmax semantics) -----------------------------
__global__ void nms_kernel(const float* __restrict__ scores, const int* __restrict__ anchors,
                           float* __restrict__ out_idx, float* __restrict__ out_prob,
                           int* __restrict__ boxes_out)
{
    __shared__ float sc[A];
    __shared__ float ay0[A], ax0[A], ay1[A], ax1[A], aarea[A];
    __shared__ float rv[256];
    __shared__ int   ri[256];
    __shared__ int   chosen;
    const int b = blockIdx.x, tid = threadIdx.x;

    for (int i = tid; i < A; i += 256) {
        sc[i] = scores[b * A + i];
        int y0 = anchors[i * 4 + 0], x0 = anchors[i * 4 + 1];
        int y1 = anchors[i * 4 + 2], x1 = anchors[i * 4 + 3];
        ay0[i] = (float)y0; ax0[i] = (float)x0;
        ay1[i] = (float)y1; ax1[i] = (float)x1;
        aarea[i] = (float)(y1 - y0) * (float)(x1 - x0);
    }
    __syncthreads();

    for (int it = 0; it < 6; it++) {
        float bv = -INFINITY; int bi = 0x7fffffff;
        for (int i = tid; i < A; i += 256) {
            if (sc[i] > bv) { bv = sc[i]; bi = i; }
        }
        rv[tid] = bv; ri[tid] = bi;
        __syncthreads();
        for (int s = 128; s > 0; s >>= 1) {
            if (tid < s) {
                if (rv[tid + s] > rv[tid] ||
                    (rv[tid + s] == rv[tid] && ri[tid + s] < ri[tid])) {
                    rv[tid] = rv[tid + s]; ri[tid] = ri[tid + s];
                }
            }
            __syncthreads();
        }
        if (tid == 0) {
            int j = ri[0];
            chosen = j;
            out_idx[b * 6 + it]  = (float)j;
            out_prob[b * 6 + it] = rv[0];
            boxes_out[(b * 6 + it) * 4 + 0] = anchors[j * 4 + 0];
            boxes_out[(b * 6 + it) * 4 + 1] = anchors[j * 4 + 1];
            boxes_out[(b * 6 + it) * 4 + 2] = anchors[j * 4 + 2];
            boxes_out[(b * 6 + it) * 4 + 3] = anchors[j * 4 + 3];
        }
        __syncthreads();
        const int j = chosen;
        const float jy0 = ay0[j], jx0 = ax0[j], jy1 = ay1[j], jx1 = ax1[j], ja = aarea[j];
        for (int i = tid; i < A; i += 256) {
            float yy0 = fmaxf(jy0, ay0[i]), xx0 = fmaxf(jx0, ax0[i]);
            float yy1 = fminf(jy1, ay1[i]), xx1 = fminf(jx1, ax1[i]);
            float inter = fmaxf(yy1 - yy0, 0.f) * fmaxf(xx1 - xx0, 0.f);
            float iou = inter / (ja + aarea[i] - inter);
            if (iou > 0.25f) sc[i] = -INFINITY;
        }
        __syncthreads();
    }
}

// ---------------- crop + bilinear resize to 224x224 ----------------------------
__device__ __forceinline__ float sample_pad(const float* __restrict__ x,
                                            int bc, int y, int xx)
{
    y -= PADI; xx -= PADI;
    if ((unsigned)y < 448u && (unsigned)xx < 448u)
        return x[(bc * 448 + y) * 448 + xx];
    return 0.f;
}

__global__ void crop_kernel(const float* __restrict__ x, const int* __restrict__ boxes,
                            float* __restrict__ parts)
{
    int idx = blockIdx.x * 256 + threadIdx.x;
    int ix = idx % 224; int t = idx / 224;
    int iy = t % 224;  t /= 224;
    int c  = t % 3;    t /= 3;
    int n  = t % 6;    int b = t / 6;

    const int* bx = boxes + (b * 6 + n) * 4;
    const int y0 = bx[0], x0 = bx[1], y1 = bx[2], x1 = bx[3];

    float ty = (float)iy / 223.f;
    float tx = (float)ix / 223.f;
    float ys = (float)y0 + ty * (float)(y1 - y0 - 1);
    float xs = (float)x0 + tx * (float)(x1 - x0 - 1);
    int y0i = (int)floorf(ys);
    int x0i = (int)floorf(xs);
    float wy = ys - (float)y0i;
    float wx = xs - (float)x0i;
    int y1i = min(y0i + 1, 895);
    int x1i = min(x0i + 1, 895);

    const int bc = b * 3 + c;
    float v00 = sample_pad(x, bc, y0i, x0i);
    float v01 = sample_pad(x, bc, y0i, x1i);
    float v10 = sample_pad(x, bc, y1i, x0i);
    float v11 = sample_pad(x, bc, y1i, x1i);

    float v = v00 * (1.f - wy) * (1.f - wx) + v01 * (1.f - wy) * wx
            + v10 * wy * (1.f - wx)         + v11 * wy * wx;
    parts[idx] = v;
}

// ---------------- launcher ------------------------------------------------------
extern "C" void kernel_launch(void* const* d_in, const int* in_sizes, int n_in,
                              void* d_out, int out_size, void* d_ws, size_t ws_size,
                              hipStream_t stream)
{
    const float* x       = (const float*)d_in[0];
    const float* rpn     = (const float*)d_in[1];
    const int*   anchors = (const int*)  d_in[2];
    const float* w1  = (const float*)d_in[3];  const float* b1  = (const float*)d_in[4];
    const float* w2  = (const float*)d_in[5];  const float* b2  = (const float*)d_in[6];
    const float* w3  = (const float*)d_in[7];  const float* b3  = (const float*)d_in[8];
    const float* wt1 = (const float*)d_in[9];  const float* bt1 = (const float*)d_in[10];
    const float* wt2 = (const float*)d_in[11]; const float* bt2 = (const float*)d_in[12];
    const float* wt3 = (const float*)d_in[13]; const float* bt3 = (const float*)d_in[14];

    float* out = (float*)d_out;
    float* d1  = (float*)d_ws;                // 401408
    float* d1t = d1  + 401408;                // 401408 (relu'd, [b][pos][co])
    float* d2  = d1t + 401408;                // 100352 (relu'd, [b][co][pos])
    float* d2t = d2  + 100352;                // 100352 (relu'd, [b][pos][co])
    float* d3t = d2t + 100352;                // 32768  (relu'd, [b][pos][co])
    int*   boxes = (int*)(d3t + 32768);       // 384 ints
    unsigned short* wh = (unsigned short*)((float*)d_ws + 1036672);  // 16B-aligned
    unsigned short* wl = wh + 2359296;

    float* scores = out;                      // 16*1614
    float* oidx   = out + 25824;
    float* oprob  = out + 25920;
    float* parts  = out + 26016;

    pack_w_kernel<<<1152, 256, 0, stream>>>(w1, wh, wl);
    init_d1_kernel<<<(B * 128 * 196 + 255) / 256, 256, 0, stream>>>(b1, d1);
    conv1_mfma_kernel<<<dim3(16, 4, 8), 256, 0, stream>>>(rpn, wh, wl, d1);
    trans_d1_kernel<<<401408 / 256, 256, 0, stream>>>(d1, d1t);
    conv2_kernel<<<dim3(16, 8), 256, 0, stream>>>(d1, w2, b2, d2, d2t);
    conv3_kernel<<<dim3(16, 8), 256, 0, stream>>>(d2, w3, b3, d3t);
    tidy_kernel<<<25824 / 4, 256, 0, stream>>>(d1t, d2t, d3t,
                                               wt1, bt1, wt2, bt2, wt3, bt3, scores);
    nms_kernel<<<16, 256, 0, stream>>>(scores, anchors, oidx, oprob, boxes);
    crop_kernel<<<(16 * 6 * 3 * 224 * 224) / 256, 256, 0, stream>>>(x, boxes, parts);
}